// Round 1
// 402.964 us; speedup vs baseline: 1.0247x; 1.0247x over previous
//
#include <hip/hip_runtime.h>
#include <hip/hip_fp16.h>
#include <math.h>

#define N_NODES 100000
#define N_EDGES 1600000
#define IN_F 256
#define OUT_F 128
#define SCAN_TPB 256
#define SCAN_EPB 1024

// hist partition: R node ranges x C edge chunks, packed 16-bit LDS bins
#define HR 4
#define HRANGE 25000          // nodes per range (50 KB LDS as packed u16)
#define HC 64
#define HCHUNK 25000          // edges per chunk (divisible by 4)
#define PWORDS (N_NODES / 2)  // packed words per chunk row (50,000)

typedef _Float16 h8 __attribute__((ext_vector_type(8)));
typedef float f4 __attribute__((ext_vector_type(4)));

// ---------------- LDS-privatized histogram, packed 16-bit bins ----------------
// grid = HC x (2 type x HR) = 512 blocks. type 0: dst (+ per-edge rank),
// type 1: src. Counts per (chunk,node) < 25000 so 16-bit halves never overflow.
__global__ __launch_bounds__(256) void hist_kernel(
        const int* __restrict__ src, const int* __restrict__ dst,
        int* __restrict__ rank, unsigned int* __restrict__ partial_in,
        unsigned int* __restrict__ partial_out) {
    __shared__ unsigned int bins[HRANGE / 2];   // 50,000 B
    int b = blockIdx.x;
    int c = b >> 3;          // 0..63 chunk
    int tr = b & 7;
    int type = tr >> 2;      // 0 = dst, 1 = src
    int r = tr & 3;          // 0..3 range
    for (int i = threadIdx.x; i < HRANGE / 2; i += 256) bins[i] = 0;
    __syncthreads();
    const int* nodes = type ? src : dst;
    const int e0 = c * HCHUNK;
    const int lo = r * HRANGE;
    const int ngroups = HCHUNK / 4;   // 6250
    for (int g = threadIdx.x; g < ngroups; g += 256) {
        int e = e0 + g * 4;
        int4 n4 = *(const int4*)(nodes + e);
        int nn[4] = {n4.x, n4.y, n4.z, n4.w};
        #pragma unroll
        for (int j = 0; j < 4; ++j) {
            unsigned loc = (unsigned)(nn[j] - lo);
            if (loc < (unsigned)HRANGE) {
                unsigned sh = (loc & 1) * 16;
                unsigned old = atomicAdd(&bins[loc >> 1], 1u << sh);
                if (type == 0) rank[e + j] = (int)((old >> sh) & 0xffffu);
            }
        }
    }
    __syncthreads();
    unsigned int* part = type ? partial_out : partial_in;
    unsigned int* dstp = part + (size_t)c * PWORDS + (lo >> 1);
    for (int i = threadIdx.x; i < HRANGE / 2; i += 256) dstp[i] = bins[i];
}

// ---------------- fused reduce: deg_in + chunk_base16 + rs_out + scan partials ----------------
// block = 256 threads x 4 nodes = 1024 nodes (matches SCAN_EPB)
__global__ __launch_bounds__(256) void fused_reduce_kernel(
        const unsigned int* __restrict__ partial_in,
        const unsigned int* __restrict__ partial_out,
        unsigned short* __restrict__ chunk_base16,
        int* __restrict__ deg_in, float* __restrict__ rs_out,
        int* __restrict__ spart, int N) {
    __shared__ int tmp[256];
    int t = threadIdx.x;
    int n0 = blockIdx.x * SCAN_EPB + t * 4;
    int run[4] = {0, 0, 0, 0};
    int sout[4] = {0, 0, 0, 0};
    if (n0 < N) {
        const int w0 = n0 >> 1;    // word offset (n0 multiple of 4 -> even)
        #pragma unroll 4
        for (int c = 0; c < HC; ++c) {
            // chunk_base = running sum of per-chunk dst counts
            ushort4 cb;
            cb.x = (unsigned short)run[0]; cb.y = (unsigned short)run[1];
            cb.z = (unsigned short)run[2]; cb.w = (unsigned short)run[3];
            *(ushort4*)(chunk_base16 + (size_t)c * N_NODES + n0) = cb;
            uint2 pi = *(const uint2*)(partial_in + (size_t)c * PWORDS + w0);
            run[0] += (int)(pi.x & 0xffffu);  run[1] += (int)(pi.x >> 16);
            run[2] += (int)(pi.y & 0xffffu);  run[3] += (int)(pi.y >> 16);
            uint2 po = *(const uint2*)(partial_out + (size_t)c * PWORDS + w0);
            sout[0] += (int)(po.x & 0xffffu); sout[1] += (int)(po.x >> 16);
            sout[2] += (int)(po.y & 0xffffu); sout[3] += (int)(po.y >> 16);
        }
        *(int4*)(deg_in + n0) = make_int4(run[0], run[1], run[2], run[3]);
        float4 rs;
        rs.x = rsqrtf((float)(sout[0] < 1 ? 1 : sout[0]));
        rs.y = rsqrtf((float)(sout[1] < 1 ? 1 : sout[1]));
        rs.z = rsqrtf((float)(sout[2] < 1 ? 1 : sout[2]));
        rs.w = rsqrtf((float)(sout[3] < 1 ? 1 : sout[3]));
        *(float4*)(rs_out + n0) = rs;
    }
    tmp[t] = run[0] + run[1] + run[2] + run[3];
    __syncthreads();
    for (int off = 128; off > 0; off >>= 1) {
        if (t < off) tmp[t] += tmp[t + off];
        __syncthreads();
    }
    if (t == 0) spart[blockIdx.x] = tmp[0];
}

// ---------------- scan over block partials + final row_ptr ----------------
__global__ __launch_bounds__(128) void scan_part2(const int* __restrict__ partials,
                                                  int* __restrict__ bases, int nb) {
    __shared__ int tmp[128];
    int t = threadIdx.x;
    int v = (t < nb) ? partials[t] : 0;
    tmp[t] = v;
    __syncthreads();
    int x = v;
    for (int off = 1; off < 128; off <<= 1) {
        int y = (t >= off) ? tmp[t - off] : 0;
        __syncthreads();
        x += y;
        tmp[t] = x;
        __syncthreads();
    }
    if (t < nb) bases[t] = x - v;   // exclusive
}

__global__ __launch_bounds__(SCAN_TPB) void scan_part3(const int* __restrict__ deg,
                                                       const int* __restrict__ bases,
                                                       int* __restrict__ row_ptr, int N) {
    __shared__ int tmp[SCAN_TPB];
    int t = threadIdx.x;
    int i0 = blockIdx.x * SCAN_EPB + t * 4;
    int v[4];
    int s = 0;
    #pragma unroll
    for (int j = 0; j < 4; ++j) { v[j] = (i0 + j < N) ? deg[i0 + j] : 0; s += v[j]; }
    tmp[t] = s;
    __syncthreads();
    int x = s;
    for (int off = 1; off < SCAN_TPB; off <<= 1) {
        int y = (t >= off) ? tmp[t - off] : 0;
        __syncthreads();
        x += y;
        tmp[t] = x;
        __syncthreads();
    }
    int excl = bases[blockIdx.x] + x - s;
    #pragma unroll
    for (int j = 0; j < 4; ++j) {
        if (i0 + j < N) row_ptr[i0 + j] = excl;
        excl += v[j];
    }
    if (blockIdx.x == gridDim.x - 1 && t == SCAN_TPB - 1) row_ptr[N] = bases[blockIdx.x] + x;
}

// ---------------- atomic-free fill: dst-grouped packed (src, ew), int4 loads ----------------
__global__ __launch_bounds__(256) void fill_kernel(
        const int* __restrict__ src, const int* __restrict__ dst,
        const float* __restrict__ ew, const int* __restrict__ row_ptr,
        const unsigned short* __restrict__ chunk_base16,
        const int* __restrict__ rank, int2* __restrict__ ed, int E) {
    int e0 = (blockIdx.x * 256 + threadIdx.x) * 4;
    if (e0 >= E) return;
    int4 s4 = *(const int4*)(src + e0);
    int4 d4 = *(const int4*)(dst + e0);
    float4 w4 = *(const float4*)(ew + e0);
    int4 r4 = *(const int4*)(rank + e0);
    int c = e0 / HCHUNK;   // groups never straddle chunks (HCHUNK % 4 == 0)
    const unsigned short* cb = chunk_base16 + (size_t)c * N_NODES;
    int dd[4] = {d4.x, d4.y, d4.z, d4.w};
    int ss[4] = {s4.x, s4.y, s4.z, s4.w};
    int rr[4] = {r4.x, r4.y, r4.z, r4.w};
    float ww[4] = {w4.x, w4.y, w4.z, w4.w};
    #pragma unroll
    for (int j = 0; j < 4; ++j) {
        int d = dd[j];
        int p = row_ptr[d] + (int)cb[d] + rr[j];
        unsigned long long v = (unsigned long long)(unsigned int)ss[j] |
                               ((unsigned long long)(unsigned int)__float_as_int(ww[j]) << 32);
        __builtin_nontemporal_store(v, (unsigned long long*)&ed[p]);
    }
}

// ---------------- Wt[n][k] = (f16) W[k][n] ----------------
__global__ void wt_kernel(const float* __restrict__ W, _Float16* __restrict__ Wt) {
    int i = blockIdx.x * blockDim.x + threadIdx.x;
    if (i < IN_F * OUT_F) {
        int n = i >> 8;
        int k = i & 255;
        Wt[i] = (_Float16)W[k * OUT_F + n];
    }
}

// ---------------- h = tanh(rs[row] * (feat @ W)), f16 MFMA, B-stationary ----------------
// Each wave owns 32 output cols (n0 = wave*32) and holds ALL of its B operand
// in registers: 2 t-tiles x 8 k-steps = 16 h8 = 64 VGPRs. The row loop then
// issues only streaming A loads + converts + MFMAs (no B traffic at all).
// rs commutes through the matmul: tanh((rs*feat)@W) == tanh(rs*(feat@W)),
// so the per-row scale moves to the epilogue (f32, on the accumulator).
__global__ __launch_bounds__(256) void gemm_mfma_kernel(
        const float* __restrict__ feat, const _Float16* __restrict__ Wt,
        const float* __restrict__ rs_out, __half* __restrict__ h, int N) {
    const int wave = threadIdx.x >> 6;
    const int lane = threadIdx.x & 63;
    const int m = lane & 15;
    const int quad = lane >> 4;
    const int n0 = wave * 32;

    // Preload B fragments for this wave's 32 columns, full K.
    h8 b[2][8];
    #pragma unroll
    for (int t = 0; t < 2; ++t)
        #pragma unroll
        for (int k = 0; k < 8; ++k)
            b[t][k] = *(const h8*)&Wt[(size_t)(n0 + t * 16 + m) * IN_F + k * 32 + quad * 8];

    const int rowbase = blockIdx.x * 64;

    #pragma unroll
    for (int pair = 0; pair < 2; ++pair) {
        const int r0 = rowbase + pair * 32;
        // A rows for the two 16-row tiles; OOB rows clamp to row 0 (their
        // MFMA results land only in OOB output rows, which are not stored).
        int ar0 = r0 + m;       if (ar0 >= N) ar0 = 0;
        int ar1 = r0 + 16 + m;  if (ar1 >= N) ar1 = 0;
        const float* ap0 = feat + (size_t)ar0 * IN_F + quad * 8;
        const float* ap1 = feat + (size_t)ar1 * IN_F + quad * 8;

        f4 acc00 = {0.f, 0.f, 0.f, 0.f}, acc01 = {0.f, 0.f, 0.f, 0.f};
        f4 acc10 = {0.f, 0.f, 0.f, 0.f}, acc11 = {0.f, 0.f, 0.f, 0.f};

        #pragma unroll
        for (int k = 0; k < 8; ++k) {
            float4 f00 = *(const float4*)(ap0 + k * 32);
            float4 f01 = *(const float4*)(ap0 + k * 32 + 4);
            float4 f10 = *(const float4*)(ap1 + k * 32);
            float4 f11 = *(const float4*)(ap1 + k * 32 + 4);
            h8 a0, a1;
            a0[0] = (_Float16)f00.x; a0[1] = (_Float16)f00.y;
            a0[2] = (_Float16)f00.z; a0[3] = (_Float16)f00.w;
            a0[4] = (_Float16)f01.x; a0[5] = (_Float16)f01.y;
            a0[6] = (_Float16)f01.z; a0[7] = (_Float16)f01.w;
            a1[0] = (_Float16)f10.x; a1[1] = (_Float16)f10.y;
            a1[2] = (_Float16)f10.z; a1[3] = (_Float16)f10.w;
            a1[4] = (_Float16)f11.x; a1[5] = (_Float16)f11.y;
            a1[6] = (_Float16)f11.z; a1[7] = (_Float16)f11.w;
            acc00 = __builtin_amdgcn_mfma_f32_16x16x32_f16(a0, b[0][k], acc00, 0, 0, 0);
            acc01 = __builtin_amdgcn_mfma_f32_16x16x32_f16(a0, b[1][k], acc01, 0, 0, 0);
            acc10 = __builtin_amdgcn_mfma_f32_16x16x32_f16(a1, b[0][k], acc10, 0, 0, 0);
            acc11 = __builtin_amdgcn_mfma_f32_16x16x32_f16(a1, b[1][k], acc11, 0, 0, 0);
        }

        #pragma unroll
        for (int tile = 0; tile < 2; ++tile) {
            const f4 aL = tile ? acc10 : acc00;   // cols n0 + m
            const f4 aR = tile ? acc11 : acc01;   // cols n0 + 16 + m
            const int crow = r0 + tile * 16 + quad * 4;
            #pragma unroll
            for (int r = 0; r < 4; ++r) {
                const int rr = crow + r;
                if (rr < N) {
                    const float rs = rs_out[rr];
                    h[(size_t)rr * OUT_F + n0 + m]      = __float2half(tanhf(aL[r] * rs));
                    h[(size_t)rr * OUT_F + n0 + 16 + m] = __float2half(tanhf(aR[r] * rs));
                }
            }
        }
    }
}

// ---------------- gather: one wave per dst node, 4 edge-slots x 4-deep unroll ----------------
__global__ __launch_bounds__(256) void gather_kernel(
        const __half* __restrict__ h, const int2* __restrict__ ed,
        const int* __restrict__ row_ptr, float* __restrict__ out, int N) {
    int wave = threadIdx.x >> 6;
    int lane = threadIdx.x & 63;
    int node = blockIdx.x * 4 + wave;
    if (node >= N) return;
    int lo = row_ptr[node];
    int hi = row_ptr[node + 1];
    int p = lane >> 4;       // edge slot 0..3
    int c = lane & 15;       // feature octet: feats 8c..8c+7
    float acc[4][8];
    #pragma unroll
    for (int g = 0; g < 4; ++g)
        #pragma unroll
        for (int i = 0; i < 8; ++i) acc[g][i] = 0.f;

    for (int j = lo; j < hi; j += 16) {
        #pragma unroll
        for (int g = 0; g < 4; ++g) {
            int jj = j + g * 4 + p;
            int2 e = (jj < hi) ? ed[jj] : make_int2(0, 0);
            float w = __int_as_float(e.y);
            int4 rrow = *(const int4*)(h + (size_t)e.x * OUT_F + c * 8);
            float2 t;
            t = __half22float2(*(__half2*)&rrow.x); acc[g][0] += w * t.x; acc[g][1] += w * t.y;
            t = __half22float2(*(__half2*)&rrow.y); acc[g][2] += w * t.x; acc[g][3] += w * t.y;
            t = __half22float2(*(__half2*)&rrow.z); acc[g][4] += w * t.x; acc[g][5] += w * t.y;
            t = __half22float2(*(__half2*)&rrow.w); acc[g][6] += w * t.x; acc[g][7] += w * t.y;
        }
    }
    float v[8];
    #pragma unroll
    for (int i = 0; i < 8; ++i) {
        v[i] = (acc[0][i] + acc[1][i]) + (acc[2][i] + acc[3][i]);
        v[i] += __shfl_xor(v[i], 16);
        v[i] += __shfl_xor(v[i], 32);
    }
    if (p == 0) {
        int deg = hi - lo; if (deg < 1) deg = 1;
        float rs = rsqrtf((float)deg);
        float* op = out + (size_t)node * OUT_F + c * 8;
        *(float4*)op       = make_float4(v[0] * rs, v[1] * rs, v[2] * rs, v[3] * rs);
        *(float4*)(op + 4) = make_float4(v[4] * rs, v[5] * rs, v[6] * rs, v[7] * rs);
    }
}

extern "C" void kernel_launch(void* const* d_in, const int* in_sizes, int n_in,
                              void* d_out, int out_size, void* d_ws, size_t ws_size,
                              hipStream_t stream) {
    const float* feat   = (const float*)d_in[0];
    const float* weight = (const float*)d_in[1];
    const float* ew     = (const float*)d_in[2];
    const int*   src    = (const int*)d_in[3];
    const int*   dst    = (const int*)d_in[4];
    float* out = (float*)d_out;

    // workspace layout with aliasing (total 46.07 MB):
    //   ed (12.8M)  overlays partial_in  (dead after fused_reduce)
    //   h  (25.6M)  overlays chunk_base16 + partial_out (dead after fill/reduce)
    char* ws = (char*)d_ws;
    float* rs_out      = (float*)(ws);                       // 400,000
    int*   deg_in      = (int*)(ws + 400000);                // 400,000
    int*   row_ptr     = (int*)(ws + 800000);                // 400,016
    int*   spart       = (int*)(ws + 1200016);               // 512
    int*   sbases      = (int*)(ws + 1200528);               // 512
    int*   rank        = (int*)(ws + 1201056);               // 6,400,000
    unsigned int* partial_in  = (unsigned int*)(ws + 7601056);   // 12,800,000
    int2*  ed          = (int2*)(ws + 7601056);                  // alias ^
    unsigned short* chunk_base16 = (unsigned short*)(ws + 20401056); // 12,800,000
    unsigned int* partial_out = (unsigned int*)(ws + 33201056);  // 12,800,000
    __half* h          = (__half*)(ws + 20401056);               // alias of cb16+p_out
    _Float16* Wt       = (_Float16*)(ws + 46001056);             // 65,536

    const int nb = (N_NODES + SCAN_EPB - 1) / SCAN_EPB;   // 98

    hist_kernel<<<2 * HR * HC, 256, 0, stream>>>(src, dst, rank, partial_in, partial_out);
    fused_reduce_kernel<<<nb, 256, 0, stream>>>(partial_in, partial_out, chunk_base16,
                                                deg_in, rs_out, spart, N_NODES);
    scan_part2<<<1, 128, 0, stream>>>(spart, sbases, nb);
    scan_part3<<<nb, SCAN_TPB, 0, stream>>>(deg_in, sbases, row_ptr, N_NODES);
    fill_kernel<<<(N_EDGES / 4 + 255) / 256, 256, 0, stream>>>(src, dst, ew, row_ptr,
                                                               chunk_base16, rank, ed, N_EDGES);
    wt_kernel<<<(IN_F * OUT_F + 255) / 256, 256, 0, stream>>>(weight, Wt);
    gemm_mfma_kernel<<<(N_NODES + 63) / 64, 256, 0, stream>>>(feat, Wt, rs_out, h, N_NODES);
    gather_kernel<<<(N_NODES + 3) / 4, 256, 0, stream>>>(h, ed, row_ptr, out, N_NODES);
}